// Round 2
// baseline (538.018 us; speedup 1.0000x reference)
//
#include <hip/hip_runtime.h>

// MeshUnpool: out[b,f,t] = sum_e feat[b,f,e] * group[b,e,t] / occ[b,t]
// B=4, NF=64, E=4000, T=6000. ALL FP32 (reference is pure fp32; round-1
// bf16 misread produced NaN). group is an exact 0.0/1.0 mask at ~0.001
// density -> sparse rank-1 formulation: stream group once (384 MB = the
// HBM floor ~61us), ballot-detect nonzero columns, and per hit (e,t) all
// 64 lanes (lane == feature f, NF == wavefront) atomicAdd feat[b,f,e]
// into t-major ws[b][t][f] (contiguous 256B per hit). Epilogue transposes
// ws -> out[b][f][t] and divides by occ.

constexpr int Bn = 4;
constexpr int NF = 64;
constexpr int En = 4000;
constexpr int Tn = 6000;
constexpr int T4 = Tn / 4;       // 1500 float4-groups per e-row
constexpr int TTILES = 6;        // ceil(1500 / 256)
constexpr int ECHUNK = 50;       // e-rows per block
constexpr int NEC = En / ECHUNK; // 80

template <bool USE_WS>
__global__ __launch_bounds__(256) void unpool_sparse(
    const float* __restrict__ feat,   // [B][NF][E]
    const float* __restrict__ group,  // [B][E][T], values exactly 0.0/1.0
    const float* __restrict__ occ,    // [B][T], values 1..3
    float* __restrict__ ws,           // [B][T][NF] accumulator (USE_WS)
    float* __restrict__ out)          // [B][NF][T] direct (fallback)
{
    const int tid  = threadIdx.x;
    const int lane = tid & 63;   // == feature index f during hit processing
    const int wave = tid >> 6;
    const int tt = blockIdx.x, ec = blockIdx.y, b = blockIdx.z;

    const int t4 = tt * 256 + tid;           // this thread's float4-group
    const bool valid = t4 < T4;
    const int wave_t4_base = tt * 256 + wave * 64;

    const uint4* __restrict__ gp =
        reinterpret_cast<const uint4*>(group) + (size_t)b * En * T4;
    const float* __restrict__ featb = feat + (size_t)b * NF * En;
    const float* __restrict__ occb  = occ + (size_t)b * Tn;
    float* __restrict__ wsb  = USE_WS ? ws + (size_t)b * Tn * NF : nullptr;
    float* __restrict__ outb = USE_WS ? nullptr : out + (size_t)b * NF * Tn;

    auto process = [&](uint4 u, int ee) {
        const unsigned long long wm = __ballot((u.x | u.y | u.z | u.w) != 0u);
        if (wm == 0ull) return;
        const float fv = featb[(size_t)lane * En + ee];  // L2-hot (feat 4 MB)
        unsigned int comps[4] = {u.x, u.y, u.z, u.w};
#pragma unroll
        for (int c = 0; c < 4; ++c) {
            unsigned long long m = __ballot(comps[c] != 0u);
            while (m) {
                const int l = __ffsll(m) - 1;
                m &= m - 1;
                const float gv = __uint_as_float(__shfl((int)comps[c], l));
                const int t_hit = (wave_t4_base + l) * 4 + c;
                if (USE_WS) {
                    // 64 lanes -> 64 consecutive floats: 4 cache sectors/hit
                    atomicAdd(&wsb[(size_t)t_hit * NF + lane], fv * gv);
                } else {
                    atomicAdd(&outb[(size_t)lane * Tn + t_hit],
                              fv * gv / occb[t_hit]);
                }
            }
        }
    };

    const int e0 = ec * ECHUNK;
    for (int e = e0; e < e0 + ECHUNK; e += 2) {
        uint4 u0 = {0, 0, 0, 0}, u1 = {0, 0, 0, 0};
        if (valid) {
            const uint4* p = gp + (size_t)e * T4 + t4;
            u0 = p[0];
            u1 = p[T4];
        }
        process(u0, e);
        process(u1, e + 1);
    }
}

// Transpose ws[b][t][f] -> out[b][f][t], dividing by occ[b][t].
__global__ __launch_bounds__(256) void finalize(
    const float* __restrict__ ws, const float* __restrict__ occ,
    float* __restrict__ out)
{
    __shared__ float tile[64][65];
    const int b  = blockIdx.y;
    const int t0 = blockIdx.x * 64;
    const int tid = threadIdx.x;
    const int c  = tid & 63;
    const int r4 = tid >> 6;  // 0..3

    const float* __restrict__ wsb = ws + (size_t)b * Tn * NF;
#pragma unroll
    for (int r = r4; r < 64; r += 4) {
        const int t = t0 + r;
        tile[r][c] = (t < Tn) ? wsb[(size_t)t * NF + c] : 0.0f;
    }
    __syncthreads();

    const int t = t0 + c;
    if (t < Tn) {
        const float inv = 1.0f / occ[(size_t)b * Tn + t];
        float* __restrict__ outb = out + (size_t)b * NF * Tn;
#pragma unroll
        for (int f = r4; f < 64; f += 4) {
            outb[(size_t)f * Tn + t] = tile[c][f] * inv;  // coalesced over c
        }
    }
}

extern "C" void kernel_launch(void* const* d_in, const int* in_sizes, int n_in,
                              void* d_out, int out_size, void* d_ws, size_t ws_size,
                              hipStream_t stream) {
    const float* feat  = (const float*)d_in[0];
    const float* group = (const float*)d_in[1];
    const float* occ   = (const float*)d_in[2];

    const size_t ws_needed = (size_t)Bn * Tn * NF * sizeof(float);  // 6.1 MB
    dim3 gs(TTILES, NEC, Bn);

    if (ws_size >= ws_needed) {
        hipMemsetAsync(d_ws, 0, ws_needed, stream);
        unpool_sparse<true><<<gs, 256, 0, stream>>>(
            feat, group, occ, (float*)d_ws, nullptr);
        finalize<<<dim3((Tn + 63) / 64, Bn), 256, 0, stream>>>(
            (const float*)d_ws, occ, (float*)d_out);
    } else {
        hipMemsetAsync(d_out, 0, (size_t)out_size * sizeof(float), stream);
        unpool_sparse<false><<<gs, 256, 0, stream>>>(
            feat, group, occ, nullptr, (float*)d_out);
    }
}

// Round 3
// 521.987 us; speedup vs baseline: 1.0307x; 1.0307x over previous
//
#include <hip/hip_runtime.h>

// MeshUnpool: out[b,f,t] = sum_e feat[b,f,e] * group[b,e,t] / occ[b,t]
// B=4, NF=64, E=4000, T=6000, all fp32. group is an exact 0.0/1.0 mask at
// ~0.001 density -> sparse rank-1 formulation: stream group once (384 MB =
// HBM floor ~61 us), ballot-detect nonzero columns, per hit (e,t) all 64
// lanes (lane == feature f, NF == wavefront) atomicAdd feat[b,f,e] into
// t-major ws[b][t][f] (256 contiguous bytes per hit). Epilogue transposes
// ws -> out[b][f][t] and divides by occ.
//
// R3: unroll 4 e-rows/iter (more loads in flight per wave) + nontemporal
// group loads (keep feat gather + ws atomics L2-hot; group is stream-once).
// Measured R2: our portion ~70 us of dur=538 (rest = harness 1.5 GB
// poison fills visible in rocprof); floor ~65 us.

constexpr int Bn = 4;
constexpr int NF = 64;
constexpr int En = 4000;
constexpr int Tn = 6000;
constexpr int T4 = Tn / 4;        // 1500 float4-groups per e-row
constexpr int TTILES = 6;         // ceil(1500 / 256)
constexpr int ECHUNK = 40;        // e-rows per block (multiple of 4)
constexpr int NEC = En / ECHUNK;  // 100

typedef unsigned int u32x4 __attribute__((ext_vector_type(4)));

template <bool USE_WS>
__global__ __launch_bounds__(256) void unpool_sparse(
    const float* __restrict__ feat,   // [B][NF][E]
    const float* __restrict__ group,  // [B][E][T], values exactly 0.0/1.0
    const float* __restrict__ occ,    // [B][T], values 1..3
    float* __restrict__ ws,           // [B][T][NF] accumulator (USE_WS)
    float* __restrict__ out)          // [B][NF][T] direct (fallback)
{
    const int tid  = threadIdx.x;
    const int lane = tid & 63;   // == feature index f during hit processing
    const int wave = tid >> 6;
    const int tt = blockIdx.x, ec = blockIdx.y, b = blockIdx.z;

    const int t4 = tt * 256 + tid;           // this thread's float4-group
    const bool valid = t4 < T4;
    const int wave_t4_base = tt * 256 + wave * 64;

    const u32x4* __restrict__ gp =
        reinterpret_cast<const u32x4*>(group) + (size_t)b * En * T4;
    const float* __restrict__ featb = feat + (size_t)b * NF * En;
    const float* __restrict__ occb  = occ + (size_t)b * Tn;
    float* __restrict__ wsb  = USE_WS ? ws + (size_t)b * Tn * NF : nullptr;
    float* __restrict__ outb = USE_WS ? nullptr : out + (size_t)b * NF * Tn;

    auto process = [&](u32x4 u, int ee) {
        const unsigned long long wm = __ballot((u.x | u.y | u.z | u.w) != 0u);
        if (wm == 0ull) return;
        const float fv = featb[(size_t)lane * En + ee];  // L2-hot (feat 4 MB)
        unsigned int comps[4] = {u.x, u.y, u.z, u.w};
#pragma unroll
        for (int c = 0; c < 4; ++c) {
            unsigned long long m = __ballot(comps[c] != 0u);
            while (m) {
                const int l = __ffsll(m) - 1;
                m &= m - 1;
                const float gv = __uint_as_float(__shfl((int)comps[c], l));
                const int t_hit = (wave_t4_base + l) * 4 + c;
                if (USE_WS) {
                    // 64 lanes -> 64 consecutive floats: ~2 lines per hit
                    atomicAdd(&wsb[(size_t)t_hit * NF + lane], fv * gv);
                } else {
                    atomicAdd(&outb[(size_t)lane * Tn + t_hit],
                              fv * gv / occb[t_hit]);
                }
            }
        }
    };

    const int e0 = ec * ECHUNK;
    for (int e = e0; e < e0 + ECHUNK; e += 4) {
        u32x4 u0 = {0, 0, 0, 0}, u1 = {0, 0, 0, 0};
        u32x4 u2 = {0, 0, 0, 0}, u3 = {0, 0, 0, 0};
        if (valid) {
            const u32x4* p = gp + (size_t)e * T4 + t4;
            u0 = __builtin_nontemporal_load(p);
            u1 = __builtin_nontemporal_load(p + T4);
            u2 = __builtin_nontemporal_load(p + 2 * T4);
            u3 = __builtin_nontemporal_load(p + 3 * T4);
        }
        process(u0, e);
        process(u1, e + 1);
        process(u2, e + 2);
        process(u3, e + 3);
    }
}

// Transpose ws[b][t][f] -> out[b][f][t], dividing by occ[b][t].
__global__ __launch_bounds__(256) void finalize(
    const float* __restrict__ ws, const float* __restrict__ occ,
    float* __restrict__ out)
{
    __shared__ float tile[64][65];
    const int b  = blockIdx.y;
    const int t0 = blockIdx.x * 64;
    const int tid = threadIdx.x;
    const int c  = tid & 63;
    const int r4 = tid >> 6;  // 0..3

    const float* __restrict__ wsb = ws + (size_t)b * Tn * NF;
#pragma unroll
    for (int r = r4; r < 64; r += 4) {
        const int t = t0 + r;
        tile[r][c] = (t < Tn) ? wsb[(size_t)t * NF + c] : 0.0f;
    }
    __syncthreads();

    const int t = t0 + c;
    if (t < Tn) {
        const float inv = 1.0f / occ[(size_t)b * Tn + t];
        float* __restrict__ outb = out + (size_t)b * NF * Tn;
#pragma unroll
        for (int f = r4; f < 64; f += 4) {
            outb[(size_t)f * Tn + t] = tile[c][f] * inv;  // coalesced over c
        }
    }
}

extern "C" void kernel_launch(void* const* d_in, const int* in_sizes, int n_in,
                              void* d_out, int out_size, void* d_ws, size_t ws_size,
                              hipStream_t stream) {
    const float* feat  = (const float*)d_in[0];
    const float* group = (const float*)d_in[1];
    const float* occ   = (const float*)d_in[2];

    const size_t ws_needed = (size_t)Bn * Tn * NF * sizeof(float);  // 6.1 MB
    dim3 gs(TTILES, NEC, Bn);

    if (ws_size >= ws_needed) {
        hipMemsetAsync(d_ws, 0, ws_needed, stream);
        unpool_sparse<true><<<gs, 256, 0, stream>>>(
            feat, group, occ, (float*)d_ws, nullptr);
        finalize<<<dim3((Tn + 63) / 64, Bn), 256, 0, stream>>>(
            (const float*)d_ws, occ, (float*)d_out);
    } else {
        hipMemsetAsync(d_out, 0, (size_t)out_size * sizeof(float), stream);
        unpool_sparse<false><<<gs, 256, 0, stream>>>(
            feat, group, occ, nullptr, (float*)d_out);
    }
}